// Round 16
// baseline (142.099 us; speedup 1.0000x reference)
//
#include <hip/hip_runtime.h>
#include <hip/hip_bf16.h>
#include <cstddef>

constexpr int B = 32, L = 512, D = 256, F = 256, T = 2048, NB = 256;
constexpr float LN_EPS = 1e-5f;
constexpr int BDIM = 256;
constexpr int WFRAGS = 24 * 16 * 64;     // MFMA B-fragments per conv layer

constexpr int N_FH  = 1024;              // final_h tiles (64 rows each)
constexpr int NT_L  = 9;                 // dur tiles per batch   (9*62 >= 512)
constexpr int NT_T  = 34;                // en/pi tiles per batch (34*62 >= 2048)
constexpr int N_DUR = NT_L * B;          // 288
constexpr int N_TP  = NT_T * B;          // 1088 per T-predictor
constexpr int N_PRED = N_DUR + 2 * N_TP; // 2464 predictor tiles (dispatch FIRST)

// preamble block regions
constexpr int PRE_WPREP = 576;           // 6 layers * 96 blocks
constexpr int PRE_XBF   = 1024;          // x -> bf16 copy (4096 floats/block)
constexpr int PRE_IDX   = 32;            // one per batch row
constexpr int PRE_TOTAL = PRE_WPREP + PRE_XBF + PRE_IDX + 1;   // +1 zv

typedef __attribute__((ext_vector_type(8))) short short8;
typedef __attribute__((ext_vector_type(4))) short short4v;
typedef __attribute__((ext_vector_type(4))) float f32x4;

__device__ inline short f2bf(float x) {
    __hip_bfloat16 h = __float2bfloat16(x);
    return __builtin_bit_cast(short, h);
}

// ===== PREAMBLE: wprep + xbf + cumsum/idx + zv in ONE dispatch ============
__global__ void preamble_kernel(const float* __restrict__ w0, const float* __restrict__ w1,
                                const float* __restrict__ w2, const float* __restrict__ w3,
                                const float* __restrict__ w4, const float* __restrict__ w5,
                                const float* __restrict__ x,
                                const int* __restrict__ dt,
                                const float* __restrict__ et, const float* __restrict__ ebins,
                                const float* __restrict__ pt, const float* __restrict__ pbins,
                                const float* __restrict__ zcb1, const float* __restrict__ zg1,
                                const float* __restrict__ zb1, const float* __restrict__ zw2,
                                const float* __restrict__ zcb2, const float* __restrict__ zg2,
                                const float* __restrict__ zb2, const float* __restrict__ zlw,
                                const float* __restrict__ zlb,
                                short* __restrict__ wb, short* __restrict__ xbf,
                                int* __restrict__ cum,
                                int* __restrict__ gidx, int* __restrict__ eidx,
                                int* __restrict__ pidx, float* __restrict__ zv) {
    __shared__ int   cs[512];
    __shared__ float z1s[256];
    __shared__ float red[8];

    const int tid = threadIdx.x;
    int id = blockIdx.x;

    // ---------------- wprep: repack conv weights to MFMA B-fragments -----
    // fcol mapping: frag n16 gives lane (lane&15) the 4 CONTIGUOUS cols
    if (id < PRE_WPREP) {
        const float* ws[6] = {w0, w1, w2, w3, w4, w5};
        const float* w = ws[id / 96];
        short* dst = wb + (size_t)(id / 96) * WFRAGS * 8;
        const int phi = (id % 96) * BDIM + tid;          // 0..24575
        const int kb = phi >> 10;
        const int n16 = (phi >> 6) & 15;
        const int lane = phi & 63;
        const int kconv = kb >> 3, dblk = kb & 7;
        const int kg = lane >> 4;
        const int fcol = (n16 >> 2) * 64 + (lane & 15) * 4 + (n16 & 3);
        const float* src = w + (size_t)kconv * D * F + (dblk * 32 + kg * 8) * F + fcol;
        short8 o;
        #pragma unroll
        for (int j = 0; j < 8; j++) o[j] = f2bf(src[j * F]);
        *(short8*)(dst + (size_t)phi * 8) = o;
        return;
    }
    id -= PRE_WPREP;

    // ---------------- xbf: bf16 copy of x (for copy-staging paths) -------
    if (id < PRE_XBF) {
        const size_t base = (size_t)id * 4096 + (size_t)tid * 16;
        const float* src = x + base;
        short* dst = xbf + base;
        #pragma unroll
        for (int i = 0; i < 4; i++) {
            const float4 v = *(const float4*)(src + i * 4);
            short4v o;
            o[0] = f2bf(v.x); o[1] = f2bf(v.y); o[2] = f2bf(v.z); o[3] = f2bf(v.w);
            *(short4v*)(dst + i * 4) = o;
        }
        return;
    }
    id -= PRE_XBF;

    // ---------------- cumsum (per b) + all index precompute --------------
    if (id < PRE_IDX) {
        const int b = id;
        cs[tid] = dt[b * L + tid];
        cs[tid + 256] = dt[b * L + tid + 256];
        __syncthreads();
        for (int off = 1; off < 512; off <<= 1) {
            const int v0 = (tid >= off) ? cs[tid - off] : 0;
            const int v1 = (tid + 256 >= off) ? cs[tid + 256 - off] : 0;
            __syncthreads();
            cs[tid] += v0; cs[tid + 256] += v1;
            __syncthreads();
        }
        cum[b * L + tid] = cs[tid];
        cum[b * L + tid + 256] = cs[tid + 256];
        #pragma unroll
        for (int i = 0; i < 8; i++) {
            const int t = tid + i * 256;
            const int r = b * T + t;
            int lo = 0, hi = L;
            while (lo < hi) { const int mid = (lo + hi) >> 1; if (cs[mid] <= t) lo = mid + 1; else hi = mid; }
            gidx[r] = (lo < L) ? lo : -1;
            const float e = et[r];
            int el = 0, eh = NB - 1;
            while (el < eh) { const int mid = (el + eh) >> 1; if (ebins[mid] < e) el = mid + 1; else eh = mid; }
            eidx[r] = el;
            const float p = pt[r];
            int pl = 0, ph = NB - 1;
            while (pl < ph) { const int mid = (pl + ph) >> 1; if (pbins[mid] < p) pl = mid + 1; else ph = mid; }
            pidx[r] = pl;
        }
        return;
    }

    // ---------------- zv: energy predictor's zero-region scalar ----------
    {
        const int f = tid;
        const int wv = f >> 6, lane = f & 63;
        float v = fmaxf(zcb1[f], 0.f);
        float s = v, q = v * v;
        #pragma unroll
        for (int msk = 1; msk < 64; msk <<= 1) { s += __shfl_xor(s, msk); q += __shfl_xor(q, msk); }
        if (lane == 0) { red[wv] = s; red[4 + wv] = q; }
        __syncthreads();
        {
            const float S = red[0] + red[1] + red[2] + red[3];
            const float Q = red[4] + red[5] + red[6] + red[7];
            const float m = S * (1.f / 256.f);
            const float var = fmaxf(Q * (1.f / 256.f) - m * m, 0.f);
            const float rs = rsqrtf(var + LN_EPS);
            z1s[f] = (v - m) * rs * zg1[f] + zb1[f];
        }
        __syncthreads();
        float y = zcb2[f];
        for (int d = 0; d < D; d++) {
            y += z1s[d] * (zw2[(size_t)d * F + f] + zw2[((size_t)D + d) * F + f]
                           + zw2[((size_t)2 * D + d) * F + f]);
        }
        v = fmaxf(y, 0.f);
        s = v; q = v * v;
        #pragma unroll
        for (int msk = 1; msk < 64; msk <<= 1) { s += __shfl_xor(s, msk); q += __shfl_xor(q, msk); }
        __syncthreads();
        if (lane == 0) { red[wv] = s; red[4 + wv] = q; }
        __syncthreads();
        const float S = red[0] + red[1] + red[2] + red[3];
        const float Q = red[4] + red[5] + red[6] + red[7];
        const float m = S * (1.f / 256.f);
        const float var = fmaxf(Q * (1.f / 256.f) - m * m, 0.f);
        const float rs = rsqrtf(var + LN_EPS);
        float p = ((v - m) * rs * zg2[f] + zb2[f]) * zlw[f];
        #pragma unroll
        for (int msk = 1; msk < 64; msk <<= 1) p += __shfl_xor(p, msk);
        __syncthreads();
        if (lane == 0) red[wv] = p;
        __syncthreads();
        if (f == 0) zv[0] = fmaxf(red[0] + red[1] + red[2] + red[3] + zlb[0], 0.f);
    }
}

// ---- 16-MFMA cluster -----------------------------------------------------
__device__ __forceinline__ void conv_mfma16(const short8 (&a)[4], const short8 (&bb)[4],
                                            f32x4 (&acc)[4][4]) {
    __builtin_amdgcn_s_setprio(1);
    #pragma unroll
    for (int m = 0; m < 4; m++)
        #pragma unroll
        for (int n = 0; n < 4; n++)
            acc[m][n] = __builtin_amdgcn_mfma_f32_16x16x32_bf16(a[m], bb[n], acc[m][n], 0, 0, 0);
    __builtin_amdgcn_s_setprio(0);
}

// ---- K=768 conv MFMA loop; wave = 64 rows x 64-col strip (round-11) -----
// Parity double-buffered B only; A read per step. ~64 VGPR + 64 AGPR =
// exactly the 4-blocks/CU budget. Round 12 proved adding A-prefetch spills
// (978 MB scratch, 2.7x regression); round 13 proved 3-blocks/CU +
// A-prefetch is net worse (occupancy > ILP here). Do not touch.
__device__ __forceinline__ void conv_kloop(const short* in_s, const short8* bw,
                                           f32x4 (&acc)[4][4], int w,
                                           int lane, int kg, int lr) {
    const short8* bp = bw + (w * 4) * 64 + lane;
    short8 bA[4], bB[4];
    #pragma unroll
    for (int n = 0; n < 4; n++) bA[n] = bp[n * 64];
    bp += 1024;
    #pragma unroll
    for (int n = 0; n < 4; n++) bB[n] = bp[n * 64];
    bp += 1024;

    #pragma unroll
    for (int kconv = 0; kconv < 3; kconv++) {
        const short* rowp = in_s + (lr + kconv) * 256;
        const int xb = (lr + kconv) & 7;
        #pragma unroll 1
        for (int db = 0; db < 8; db += 2) {
            short8 a[4];
            {
                const short* ab = rowp + (((db * 4 + kg) ^ xb) << 3);
                #pragma unroll
                for (int m = 0; m < 4; m++) a[m] = *(const short8*)(ab + m * 4096);
                conv_mfma16(a, bA, acc);
                #pragma unroll
                for (int n = 0; n < 4; n++) bA[n] = bp[n * 64];
                bp += 1024;
            }
            {
                const short* ab = rowp + ((((db + 1) * 4 + kg) ^ xb) << 3);
                #pragma unroll
                for (int m = 0; m < 4; m++) a[m] = *(const short8*)(ab + m * 4096);
                conv_mfma16(a, bB, acc);
                #pragma unroll
                for (int n = 0; n < 4; n++) bB[n] = bp[n * 64];
                bp += 1024;
            }
        }
    }
}

struct PredParams {
    const short* wb1; const short* wb2;
    const float *cb1, *g1, *b1, *cb2, *g2, *b2, *lw, *lb;
    const int* eidx; const float* emb;   // emb != nullptr -> add emb during staging
    const float* zv;                     // non-null -> zero-region scalar skip (energy)
    float* out;
    int Tlen;                            // 512 (dur) or 2048 (en/pi)
    int mode;                            // 0: direct rows; 1: gather
};

// ===== MEGA KERNEL: dur/en/pi predictor tiles FIRST, final_h tiles LAST ==
__launch_bounds__(BDIM, 4)
__global__ void mega_kernel(const float* __restrict__ xin,
                            const short* __restrict__ xbf,
                            const int* __restrict__ gidx,
                            const int* __restrict__ cum,
                            const int* __restrict__ eidxA,
                            const int* __restrict__ pidxA,
                            const float* __restrict__ eemb,
                            const float* __restrict__ pemb,
                            float* __restrict__ h,
                            PredParams pd, PredParams pe, PredParams pp) {
    __shared__ short in_s[66 * 256];            // 33.8 KB: x-tile then conv1-LN tile
    __shared__ float red_s[4][64], red_q[4][64];
    __shared__ float row_m[64], row_rs[64];
    __shared__ float dot_p[4][64];

    const int tid = threadIdx.x;
    const int w = tid >> 6, lane = tid & 63;

    int id = blockIdx.x;
    // ---------------- final_h streaming tiles (tail of the grid) --------
    if (id >= N_PRED) {
        const int fid = id - N_PRED;
        const int row0 = fid * 64 + w * 16;
        #pragma unroll 4
        for (int i = 0; i < 16; i++) {
            const int row = row0 + i;                    // b*T + t
            const int b = row >> 11;
            const int g = gidx[row], ei = eidxA[row], pi = pidxA[row];
            float4 v = make_float4(0.f, 0.f, 0.f, 0.f);
            if (g >= 0) v = *(const float4*)(xin + ((size_t)b * L + g) * D + lane * 4);
            const float4 ev = *(const float4*)(eemb + (size_t)ei * D + lane * 4);
            const float4 pv = *(const float4*)(pemb + (size_t)pi * D + lane * 4);
            v.x += ev.x + pv.x; v.y += ev.y + pv.y; v.z += ev.z + pv.z; v.w += ev.w + pv.w;
            *(float4*)(h + (size_t)row * D + lane * 4) = v;
        }
        return;
    }

    // ---------------- predictor tile decode ----------------
    PredParams P;
    int b, tx;
    if (id < N_DUR) {
        P = pd; b = id / NT_L; tx = id % NT_L;
    } else if (id < N_DUR + N_TP) {
        id -= N_DUR;
        P = pe; b = id / NT_T; tx = id % NT_T;
    } else {
        id -= N_DUR + N_TP;
        P = pp; b = id / NT_T; tx = id % NT_T;
    }
    const int Tlen = P.Tlen;
    const int t0 = tx * 62;
    const int kg = lane >> 4, lr = lane & 15;

    // ---- zero-region skip (energy): whole window past total duration ----
    if (P.zv != nullptr) {
        const int ctot = cum[(b + 1) * L - 1];
        if (t0 - 2 >= ctot) {
            if (tid < 62) {
                const int t = t0 + tid;
                if (t < Tlen) P.out[(size_t)b * Tlen + t] = P.zv[0];
            }
            return;
        }
    }

    // ---- stage 66 input rows (t = t0-2 .. t0+63) as bf16, XOR-swizzled ---
    constexpr int TASKS = 66 * 32;
    constexpr int BATCH = 4;
    const bool has_emb = (P.emb != nullptr);
    if (!has_emb) {
        // copy-staging from xbf (dur: direct rows; energy: gather rows)
        for (int base = 0; base < TASKS; base += BATCH * BDIM) {
            short8 vb[BATCH];
            #pragma unroll
            for (int j = 0; j < BATCH; j++) {
                vb[j] = short8{};
                const int task = base + j * BDIM + tid;
                if (task < TASKS) {
                    const int row = task >> 5, slot = task & 31;
                    const int t = t0 - 2 + row;
                    if (t >= 0 && t < Tlen) {
                        const int src = (P.mode == 0) ? t : gidx[b * T + t];
                        if (src >= 0)
                            vb[j] = *(const short8*)(xbf + ((size_t)b * L + src) * D + slot * 8);
                    }
                }
            }
            #pragma unroll
            for (int j = 0; j < BATCH; j++) {
                const int task = base + j * BDIM + tid;
                if (task < TASKS) {
                    const int row = task >> 5, slot = task & 31;
                    *(short8*)(in_s + row * 256 + ((slot ^ (row & 7)) << 3)) = vb[j];
                }
            }
        }
    } else {
        // fp32 gather + emb add staging (pitch)
        for (int base = 0; base < TASKS; base += BATCH * BDIM) {
            float4 fa[BATCH], fb[BATCH], ea[BATCH], eb[BATCH];
            #pragma unroll
            for (int j = 0; j < BATCH; j++) {
                fa[j] = make_float4(0.f, 0.f, 0.f, 0.f); fb[j] = fa[j];
                ea[j] = fa[j]; eb[j] = fa[j];
                const int task = base + j * BDIM + tid;
                if (task < TASKS) {
                    const int row = task >> 5, slot = task & 31;
                    const int t = t0 - 2 + row;
                    if (t >= 0 && t < Tlen) {
                        const int g = gidx[b * T + t];
                        if (g >= 0) {
                            const float* p = xin + ((size_t)b * L + g) * D + slot * 8;
                            fa[j] = *(const float4*)p; fb[j] = *(const float4*)(p + 4);
                        }
                        const float* er = P.emb + (size_t)P.eidx[b * T + t] * F + slot * 8;
                        ea[j] = *(const float4*)er; eb[j] = *(const float4*)(er + 4);
                    }
                }
            }
            #pragma unroll
            for (int j = 0; j < BATCH; j++) {
                const int task = base + j * BDIM + tid;
                if (task < TASKS) {
                    const int row = task >> 5, slot = task & 31;
                    short8 frag;
                    frag[0] = f2bf(fa[j].x + ea[j].x); frag[1] = f2bf(fa[j].y + ea[j].y);
                    frag[2] = f2bf(fa[j].z + ea[j].z); frag[3] = f2bf(fa[j].w + ea[j].w);
                    frag[4] = f2bf(fb[j].x + eb[j].x); frag[5] = f2bf(fb[j].y + eb[j].y);
                    frag[6] = f2bf(fb[j].z + eb[j].z); frag[7] = f2bf(fb[j].w + eb[j].w);
                    *(short8*)(in_s + row * 256 + ((slot ^ (row & 7)) << 3)) = frag;
                }
            }
        }
    }
    __syncthreads();

    // ---- conv1 K-loop ----
    f32x4 acc[4][4];
    #pragma unroll
    for (int m = 0; m < 4; m++)
        #pragma unroll
        for (int n = 0; n < 4; n++)
            acc[m][n] = (f32x4){0.f, 0.f, 0.f, 0.f};
    conv_kloop(in_s, (const short8*)P.wb1, acc, w, lane, kg, lr);

    // ---- epilogue1: bias+ReLU, LN1 stats, write LN rows back to in_s ----
    const int cbase = w * 64 + lr * 4;                  // 4 contiguous cols
    const f32x4 c1v = *(const f32x4*)(P.cb1 + cbase);
    const f32x4 g1v = *(const f32x4*)(P.g1 + cbase);
    const f32x4 b1v = *(const f32x4*)(P.b1 + cbase);

    #pragma unroll
    for (int m = 0; m < 4; m++) {
        #pragma unroll
        for (int reg = 0; reg < 4; reg++) {
            float s = 0.f, q = 0.f;
            #pragma unroll
            for (int n = 0; n < 4; n++) {
                const float v = fmaxf(acc[m][n][reg] + c1v[n], 0.f);
                acc[m][n][reg] = v;
                s += v; q += v * v;
            }
            #pragma unroll
            for (int msk = 1; msk < 16; msk <<= 1) { s += __shfl_xor(s, msk); q += __shfl_xor(q, msk); }
            if (lr == 0) {
                const int r = m * 16 + kg * 4 + reg;
                red_s[w][r] = s; red_q[w][r] = q;
            }
        }
    }
    __syncthreads();                                       // x-tile in in_s now dead
    if (tid < 64) {
        const float s = red_s[0][tid] + red_s[1][tid] + red_s[2][tid] + red_s[3][tid];
        const float q = red_q[0][tid] + red_q[1][tid] + red_q[2][tid] + red_q[3][tid];
        const float mm = s * (1.f / 256.f);
        const float var = fmaxf(q * (1.f / 256.f) - mm * mm, 0.f);
        row_m[tid] = mm;
        row_rs[tid] = rsqrtf(var + LN_EPS);
    }
    if (tid >= 128 && tid < 192) {                         // zero c1 rows 64,65
        short8 z = {};
        *(short8*)(in_s + 64 * 256 + (tid - 128) * 8) = z;
    }
    __syncthreads();

    // write LN1 rows (bf16, short4 per (m,reg)) into in_s rows 0..63
    #pragma unroll
    for (int m = 0; m < 4; m++) {
        #pragma unroll
        for (int reg = 0; reg < 4; reg++) {
            const int r1 = m * 16 + kg * 4 + reg;
            const int tg = t0 - 1 + r1;
            const bool ok = (tg >= 0) && (tg < Tlen);
            const float mm = row_m[r1], rs = row_rs[r1];
            short4v o;
            #pragma unroll
            for (int n = 0; n < 4; n++) {
                const float v = ok ? (acc[m][n][reg] - mm) * rs * g1v[n] + b1v[n] : 0.f;
                o[n] = f2bf(v);
            }
            *(short4v*)(in_s + r1 * 256 + (((cbase >> 3) ^ (r1 & 7)) << 3) + (cbase & 7)) = o;
        }
    }
    __syncthreads();

    // ---- conv2 K-loop ----
    #pragma unroll
    for (int m = 0; m < 4; m++)
        #pragma unroll
        for (int n = 0; n < 4; n++)
            acc[m][n] = (f32x4){0.f, 0.f, 0.f, 0.f};
    conv_kloop(in_s, (const short8*)P.wb2, acc, w, lane, kg, lr);

    // ---- epilogue2: bias+ReLU, LN2, dot(lw)+lb+ReLU -> scalar ----
    const f32x4 c2v = *(const f32x4*)(P.cb2 + cbase);
    const f32x4 g2v = *(const f32x4*)(P.g2 + cbase);
    const f32x4 b2v = *(const f32x4*)(P.b2 + cbase);
    const f32x4 lwv = *(const f32x4*)(P.lw + cbase);

    #pragma unroll
    for (int m = 0; m < 4; m++) {
        #pragma unroll
        for (int reg = 0; reg < 4; reg++) {
            float s = 0.f, q = 0.f;
            #pragma unroll
            for (int n = 0; n < 4; n++) {
                const float v = fmaxf(acc[m][n][reg] + c2v[n], 0.f);
                acc[m][n][reg] = v;
                s += v; q += v * v;
            }
            #pragma unroll
            for (int msk = 1; msk < 16; msk <<= 1) { s += __shfl_xor(s, msk); q += __shfl_xor(q, msk); }
            if (lr == 0) {
                const int r = m * 16 + kg * 4 + reg;
                red_s[w][r] = s; red_q[w][r] = q;
            }
        }
    }
    __syncthreads();
    if (tid < 64) {
        const float s = red_s[0][tid] + red_s[1][tid] + red_s[2][tid] + red_s[3][tid];
        const float q = red_q[0][tid] + red_q[1][tid] + red_q[2][tid] + red_q[3][tid];
        const float mm = s * (1.f / 256.f);
        const float var = fmaxf(q * (1.f / 256.f) - mm * mm, 0.f);
        row_m[tid] = mm;
        row_rs[tid] = rsqrtf(var + LN_EPS);
    }
    __syncthreads();
    #pragma unroll
    for (int m = 0; m < 4; m++) {
        #pragma unroll
        for (int reg = 0; reg < 4; reg++) {
            const int r = m * 16 + kg * 4 + reg;
            const float mm = row_m[r], rs = row_rs[r];
            float p = 0.f;
            #pragma unroll
            for (int n = 0; n < 4; n++)
                p += ((acc[m][n][reg] - mm) * rs * g2v[n] + b2v[n]) * lwv[n];
            #pragma unroll
            for (int msk = 1; msk < 16; msk <<= 1) p += __shfl_xor(p, msk);
            if (lr == 0) dot_p[w][r] = p;
        }
    }
    __syncthreads();
    if (tid < 62) {
        const int t = t0 + tid;
        if (t < Tlen) {
            const float p = dot_p[0][tid] + dot_p[1][tid] + dot_p[2][tid] + dot_p[3][tid] + P.lb[0];
            P.out[(size_t)b * Tlen + t] = fmaxf(p, 0.f);
        }
    }
}

extern "C" void kernel_launch(void* const* d_in, const int* in_sizes, int n_in,
                              void* d_out, int out_size, void* d_ws, size_t ws_size,
                              hipStream_t stream) {
    const float* x        = (const float*)d_in[0];
    const int*   d_target = (const int*)d_in[1];
    const float* e_target = (const float*)d_in[2];
    const float* p_target = (const float*)d_in[3];

    const float* const* P = (const float* const*)d_in;
    const float* en_emb  = (const float*)d_in[35];
    const float* pi_emb  = (const float*)d_in[36];
    const float* en_bins = (const float*)d_in[37];
    const float* pi_bins = (const float*)d_in[38];

    float* out = (float*)d_out;
    float* h        = out;                                   // B*T*D fp32
    float* log_dur  = out + (size_t)B * T * D;               // B*L
    float* pitch    = log_dur + (size_t)B * L;               // B*T
    float* energy   = pitch + (size_t)B * T;                 // B*T

    short* wbs  = (short*)d_ws;                              // 6 * WFRAGS * 8 shorts
    int*   cum  = (int*)(wbs + (size_t)6 * WFRAGS * 8);      // B*L
    int*   gidx = cum + B * L;                               // B*T
    int*   eidx = gidx + B * T;                              // B*T
    int*   pidx = eidx + B * T;                              // B*T
    float* zvp  = (float*)(pidx + B * T);                    // 16 floats pad
    short* xbf  = (short*)(zvp + 16);                        // B*L*D bf16 (8.4 MB)

    // ONE preamble dispatch: wprep + xbf + cumsum/idx + zv
    preamble_kernel<<<PRE_TOTAL, BDIM, 0, stream>>>(
        P[5], P[9], P[15], P[19], P[25], P[29], x,
        d_target, e_target, en_bins, p_target, pi_bins,
        P[16], P[17], P[18], P[19], P[20], P[21], P[22], P[23], P[24],
        wbs, xbf, cum, gidx, eidx, pidx, zvp);

    PredParams dur_p = { wbs + (size_t)0 * WFRAGS * 8, wbs + (size_t)1 * WFRAGS * 8,
                         P[6], P[7], P[8], P[10], P[11], P[12], P[13], P[14],
                         nullptr, nullptr, nullptr, log_dur, L, 0 };
    PredParams en_p  = { wbs + (size_t)2 * WFRAGS * 8, wbs + (size_t)3 * WFRAGS * 8,
                         P[16], P[17], P[18], P[20], P[21], P[22], P[23], P[24],
                         nullptr, nullptr, zvp, energy, T, 1 };
    PredParams pi_p  = { wbs + (size_t)4 * WFRAGS * 8, wbs + (size_t)5 * WFRAGS * 8,
                         P[26], P[27], P[28], P[30], P[31], P[32], P[33], P[34],
                         eidx, en_emb, nullptr, pitch, T, 1 };

    // ONE mega dispatch: predictors first, final_h streaming tail
    mega_kernel<<<N_PRED + N_FH, BDIM, 0, stream>>>(
        x, xbf, gidx, cum, eidx, pidx, en_emb, pi_emb, h, dur_p, en_p, pi_p);
}

// Round 17
// 138.639 us; speedup vs baseline: 1.0250x; 1.0250x over previous
//
#include <hip/hip_runtime.h>
#include <hip/hip_bf16.h>
#include <cstddef>

constexpr int B = 32, L = 512, D = 256, F = 256, T = 2048, NB = 256;
constexpr float LN_EPS = 1e-5f;
constexpr int BDIM = 256;
constexpr int WFRAGS = 24 * 16 * 64;     // MFMA B-fragments per conv layer

constexpr int N_FH  = 1024;              // final_h tiles (64 rows each)
constexpr int NT_L  = 9;                 // dur tiles per batch   (9*62 >= 512)
constexpr int NT_T  = 34;                // en/pi tiles per batch (34*62 >= 2048)
constexpr int N_DUR = NT_L * B;          // 288
constexpr int N_TP  = NT_T * B;          // 1088 per T-predictor
constexpr int N_PRED = N_DUR + 2 * N_TP; // 2464 predictor tiles (dispatch FIRST)

// preamble block regions
constexpr int PRE_WPREP = 576;           // 6 layers * 96 blocks
constexpr int PRE_IDX   = 32;            // one per batch row
constexpr int PRE_TOTAL = PRE_WPREP + PRE_IDX + 1;   // +1 zv

typedef __attribute__((ext_vector_type(8))) short short8;
typedef __attribute__((ext_vector_type(4))) short short4v;
typedef __attribute__((ext_vector_type(4))) float f32x4;

__device__ inline short f2bf(float x) {
    __hip_bfloat16 h = __float2bfloat16(x);
    return __builtin_bit_cast(short, h);
}

// ===== PREAMBLE: wprep + cumsum/idx + zv in ONE dispatch ==================
__global__ void preamble_kernel(const float* __restrict__ w0, const float* __restrict__ w1,
                                const float* __restrict__ w2, const float* __restrict__ w3,
                                const float* __restrict__ w4, const float* __restrict__ w5,
                                const int* __restrict__ dt,
                                const float* __restrict__ et, const float* __restrict__ ebins,
                                const float* __restrict__ pt, const float* __restrict__ pbins,
                                const float* __restrict__ zcb1, const float* __restrict__ zg1,
                                const float* __restrict__ zb1, const float* __restrict__ zw2,
                                const float* __restrict__ zcb2, const float* __restrict__ zg2,
                                const float* __restrict__ zb2, const float* __restrict__ zlw,
                                const float* __restrict__ zlb,
                                short* __restrict__ wb, int* __restrict__ cum,
                                int* __restrict__ gidx, int* __restrict__ eidx,
                                int* __restrict__ pidx, float* __restrict__ zv) {
    __shared__ int   cs[512];
    __shared__ float z1s[256];
    __shared__ float red[8];

    const int tid = threadIdx.x;
    int id = blockIdx.x;

    // ---------------- wprep: repack conv weights to MFMA B-fragments -----
    // fcol mapping: frag n16 gives lane (lane&15) the 4 CONTIGUOUS cols
    // (n16>>2)*64 + (lane&15)*4 + (n16&3)  -> epilogue col = w*64 + lr*4 + n
    if (id < PRE_WPREP) {
        const float* ws[6] = {w0, w1, w2, w3, w4, w5};
        const float* w = ws[id / 96];
        short* dst = wb + (size_t)(id / 96) * WFRAGS * 8;
        const int phi = (id % 96) * BDIM + tid;          // 0..24575
        const int kb = phi >> 10;
        const int n16 = (phi >> 6) & 15;
        const int lane = phi & 63;
        const int kconv = kb >> 3, dblk = kb & 7;
        const int kg = lane >> 4;
        const int fcol = (n16 >> 2) * 64 + (lane & 15) * 4 + (n16 & 3);
        const float* src = w + (size_t)kconv * D * F + (dblk * 32 + kg * 8) * F + fcol;
        short8 o;
        #pragma unroll
        for (int j = 0; j < 8; j++) o[j] = f2bf(src[j * F]);
        *(short8*)(dst + (size_t)phi * 8) = o;
        return;
    }
    id -= PRE_WPREP;

    // ---------------- cumsum (per b) + all index precompute --------------
    if (id < PRE_IDX) {
        const int b = id;
        cs[tid] = dt[b * L + tid];
        cs[tid + 256] = dt[b * L + tid + 256];
        __syncthreads();
        for (int off = 1; off < 512; off <<= 1) {
            const int v0 = (tid >= off) ? cs[tid - off] : 0;
            const int v1 = (tid + 256 >= off) ? cs[tid + 256 - off] : 0;
            __syncthreads();
            cs[tid] += v0; cs[tid + 256] += v1;
            __syncthreads();
        }
        cum[b * L + tid] = cs[tid];
        cum[b * L + tid + 256] = cs[tid + 256];
        #pragma unroll
        for (int i = 0; i < 8; i++) {
            const int t = tid + i * 256;
            const int r = b * T + t;
            int lo = 0, hi = L;
            while (lo < hi) { const int mid = (lo + hi) >> 1; if (cs[mid] <= t) lo = mid + 1; else hi = mid; }
            gidx[r] = (lo < L) ? lo : -1;
            const float e = et[r];
            int el = 0, eh = NB - 1;
            while (el < eh) { const int mid = (el + eh) >> 1; if (ebins[mid] < e) el = mid + 1; else eh = mid; }
            eidx[r] = el;
            const float p = pt[r];
            int pl = 0, ph = NB - 1;
            while (pl < ph) { const int mid = (pl + ph) >> 1; if (pbins[mid] < p) pl = mid + 1; else ph = mid; }
            pidx[r] = pl;
        }
        return;
    }

    // ---------------- zv: energy predictor's zero-region scalar ----------
    {
        const int f = tid;
        const int wv = f >> 6, lane = f & 63;
        float v = fmaxf(zcb1[f], 0.f);
        float s = v, q = v * v;
        #pragma unroll
        for (int msk = 1; msk < 64; msk <<= 1) { s += __shfl_xor(s, msk); q += __shfl_xor(q, msk); }
        if (lane == 0) { red[wv] = s; red[4 + wv] = q; }
        __syncthreads();
        {
            const float S = red[0] + red[1] + red[2] + red[3];
            const float Q = red[4] + red[5] + red[6] + red[7];
            const float m = S * (1.f / 256.f);
            const float var = fmaxf(Q * (1.f / 256.f) - m * m, 0.f);
            const float rs = rsqrtf(var + LN_EPS);
            z1s[f] = (v - m) * rs * zg1[f] + zb1[f];
        }
        __syncthreads();
        float y = zcb2[f];
        for (int d = 0; d < D; d++) {
            y += z1s[d] * (zw2[(size_t)d * F + f] + zw2[((size_t)D + d) * F + f]
                           + zw2[((size_t)2 * D + d) * F + f]);
        }
        v = fmaxf(y, 0.f);
        s = v; q = v * v;
        #pragma unroll
        for (int msk = 1; msk < 64; msk <<= 1) { s += __shfl_xor(s, msk); q += __shfl_xor(q, msk); }
        __syncthreads();
        if (lane == 0) { red[wv] = s; red[4 + wv] = q; }
        __syncthreads();
        const float S = red[0] + red[1] + red[2] + red[3];
        const float Q = red[4] + red[5] + red[6] + red[7];
        const float m = S * (1.f / 256.f);
        const float var = fmaxf(Q * (1.f / 256.f) - m * m, 0.f);
        const float rs = rsqrtf(var + LN_EPS);
        float p = ((v - m) * rs * zg2[f] + zb2[f]) * zlw[f];
        #pragma unroll
        for (int msk = 1; msk < 64; msk <<= 1) p += __shfl_xor(p, msk);
        __syncthreads();
        if (lane == 0) red[wv] = p;
        __syncthreads();
        if (f == 0) zv[0] = fmaxf(red[0] + red[1] + red[2] + red[3] + zlb[0], 0.f);
    }
}

// ---- 16-MFMA cluster -----------------------------------------------------
__device__ __forceinline__ void conv_mfma16(const short8 (&a)[4], const short8 (&bb)[4],
                                            f32x4 (&acc)[4][4]) {
    __builtin_amdgcn_s_setprio(1);
    #pragma unroll
    for (int m = 0; m < 4; m++)
        #pragma unroll
        for (int n = 0; n < 4; n++)
            acc[m][n] = __builtin_amdgcn_mfma_f32_16x16x32_bf16(a[m], bb[n], acc[m][n], 0, 0, 0);
    __builtin_amdgcn_s_setprio(0);
}

// ---- K=768 conv MFMA loop; wave = 64 rows x 64-col strip -----------------
// Parity double-buffered B only; A read per step. ~64 VGPR + 64 AGPR =
// exactly the 4-blocks/CU budget. Round 12 proved adding A-prefetch spills
// (978 MB scratch, 2.7x regression); round 13 proved 3-blocks/CU +
// A-prefetch is net worse (occupancy > ILP here); round 16 proved the
// staging fp32->bf16 VALU is NOT on the critical path. Do not touch.
__device__ __forceinline__ void conv_kloop(const short* in_s, const short8* bw,
                                           f32x4 (&acc)[4][4], int w,
                                           int lane, int kg, int lr) {
    const short8* bp = bw + (w * 4) * 64 + lane;
    short8 bA[4], bB[4];
    #pragma unroll
    for (int n = 0; n < 4; n++) bA[n] = bp[n * 64];
    bp += 1024;
    #pragma unroll
    for (int n = 0; n < 4; n++) bB[n] = bp[n * 64];
    bp += 1024;

    #pragma unroll
    for (int kconv = 0; kconv < 3; kconv++) {
        const short* rowp = in_s + (lr + kconv) * 256;
        const int xb = (lr + kconv) & 7;
        #pragma unroll 1
        for (int db = 0; db < 8; db += 2) {
            short8 a[4];
            {
                const short* ab = rowp + (((db * 4 + kg) ^ xb) << 3);
                #pragma unroll
                for (int m = 0; m < 4; m++) a[m] = *(const short8*)(ab + m * 4096);
                conv_mfma16(a, bA, acc);
                #pragma unroll
                for (int n = 0; n < 4; n++) bA[n] = bp[n * 64];
                bp += 1024;
            }
            {
                const short* ab = rowp + ((((db + 1) * 4 + kg) ^ xb) << 3);
                #pragma unroll
                for (int m = 0; m < 4; m++) a[m] = *(const short8*)(ab + m * 4096);
                conv_mfma16(a, bB, acc);
                #pragma unroll
                for (int n = 0; n < 4; n++) bB[n] = bp[n * 64];
                bp += 1024;
            }
        }
    }
}

struct PredParams {
    const short* wb1; const short* wb2;
    const float *cb1, *g1, *b1, *cb2, *g2, *b2, *lw, *lb;
    const int* eidx; const float* emb;   // emb != nullptr -> add emb during staging
    const float* zv;                     // non-null -> zero-region scalar skip (energy)
    float* out;
    int Tlen;                            // 512 (dur) or 2048 (en/pi)
    int mode;                            // 0: direct rows from x; 1: gather
};

// ===== MEGA KERNEL: dur/en/pi predictor tiles FIRST, final_h tiles LAST ==
// Heavy conv tiles dispatch first so they start immediately; the short
// memory-bound final_h tiles backfill the tail as conv blocks drain.
__launch_bounds__(BDIM, 4)
__global__ void mega_kernel(const float* __restrict__ xin,
                            const int* __restrict__ gidx,
                            const int* __restrict__ cum,
                            const int* __restrict__ eidxA,
                            const int* __restrict__ pidxA,
                            const float* __restrict__ eemb,
                            const float* __restrict__ pemb,
                            float* __restrict__ h,
                            PredParams pd, PredParams pe, PredParams pp) {
    __shared__ short in_s[66 * 256];            // 33.8 KB: x-tile then conv1-LN tile
    __shared__ float red_s[4][64], red_q[4][64];
    __shared__ float row_m[64], row_rs[64];
    __shared__ float dot_p[4][64];

    const int tid = threadIdx.x;
    const int w = tid >> 6, lane = tid & 63;

    int id = blockIdx.x;
    // ---------------- final_h streaming tiles (tail of the grid) --------
    if (id >= N_PRED) {
        const int fid = id - N_PRED;
        const int row0 = fid * 64 + w * 16;
        #pragma unroll 4
        for (int i = 0; i < 16; i++) {
            const int row = row0 + i;                    // b*T + t
            const int b = row >> 11;
            const int g = gidx[row], ei = eidxA[row], pi = pidxA[row];
            float4 v = make_float4(0.f, 0.f, 0.f, 0.f);
            if (g >= 0) v = *(const float4*)(xin + ((size_t)b * L + g) * D + lane * 4);
            const float4 ev = *(const float4*)(eemb + (size_t)ei * D + lane * 4);
            const float4 pv = *(const float4*)(pemb + (size_t)pi * D + lane * 4);
            v.x += ev.x + pv.x; v.y += ev.y + pv.y; v.z += ev.z + pv.z; v.w += ev.w + pv.w;
            *(float4*)(h + (size_t)row * D + lane * 4) = v;
        }
        return;
    }

    // ---------------- predictor tile decode ----------------
    PredParams P;
    int b, tx;
    if (id < N_DUR) {
        P = pd; b = id / NT_L; tx = id % NT_L;
    } else if (id < N_DUR + N_TP) {
        id -= N_DUR;
        P = pe; b = id / NT_T; tx = id % NT_T;
    } else {
        id -= N_DUR + N_TP;
        P = pp; b = id / NT_T; tx = id % NT_T;
    }
    const int Tlen = P.Tlen;
    const int t0 = tx * 62;
    const int kg = lane >> 4, lr = lane & 15;

    // ---- zero-region skip (energy): whole window past total duration ----
    if (P.zv != nullptr) {
        const int ctot = cum[(b + 1) * L - 1];
        if (t0 - 2 >= ctot) {
            if (tid < 62) {
                const int t = t0 + tid;
                if (t < Tlen) P.out[(size_t)b * Tlen + t] = P.zv[0];
            }
            return;
        }
    }

    // ---- stage 66 input rows (t = t0-2 .. t0+63) as bf16, XOR-swizzled ---
    constexpr int TASKS = 66 * 32;
    constexpr int BATCH = 4;
    const bool has_emb = (P.emb != nullptr);
    for (int base = 0; base < TASKS; base += BATCH * BDIM) {
        float4 fa[BATCH], fb[BATCH], ea[BATCH], eb[BATCH];
        #pragma unroll
        for (int j = 0; j < BATCH; j++) {
            fa[j] = make_float4(0.f, 0.f, 0.f, 0.f); fb[j] = fa[j];
            ea[j] = fa[j]; eb[j] = fa[j];
            const int task = base + j * BDIM + tid;
            if (task < TASKS) {
                const int row = task >> 5, slot = task & 31;
                const int t = t0 - 2 + row;
                if (t >= 0 && t < Tlen) {
                    if (P.mode == 0) {
                        const float* p = xin + ((size_t)b * Tlen + t) * D + slot * 8;
                        fa[j] = *(const float4*)p; fb[j] = *(const float4*)(p + 4);
                    } else {
                        const int g = gidx[b * T + t];
                        if (g >= 0) {
                            const float* p = xin + ((size_t)b * L + g) * D + slot * 8;
                            fa[j] = *(const float4*)p; fb[j] = *(const float4*)(p + 4);
                        }
                        if (has_emb) {
                            const float* er = P.emb + (size_t)P.eidx[b * T + t] * F + slot * 8;
                            ea[j] = *(const float4*)er; eb[j] = *(const float4*)(er + 4);
                        }
                    }
                }
            }
        }
        #pragma unroll
        for (int j = 0; j < BATCH; j++) {
            const int task = base + j * BDIM + tid;
            if (task < TASKS) {
                const int row = task >> 5, slot = task & 31;
                short8 frag;
                frag[0] = f2bf(fa[j].x + ea[j].x); frag[1] = f2bf(fa[j].y + ea[j].y);
                frag[2] = f2bf(fa[j].z + ea[j].z); frag[3] = f2bf(fa[j].w + ea[j].w);
                frag[4] = f2bf(fb[j].x + eb[j].x); frag[5] = f2bf(fb[j].y + eb[j].y);
                frag[6] = f2bf(fb[j].z + eb[j].z); frag[7] = f2bf(fb[j].w + eb[j].w);
                *(short8*)(in_s + row * 256 + ((slot ^ (row & 7)) << 3)) = frag;
            }
        }
    }
    __syncthreads();

    // ---- conv1 K-loop ----
    f32x4 acc[4][4];
    #pragma unroll
    for (int m = 0; m < 4; m++)
        #pragma unroll
        for (int n = 0; n < 4; n++)
            acc[m][n] = (f32x4){0.f, 0.f, 0.f, 0.f};
    conv_kloop(in_s, (const short8*)P.wb1, acc, w, lane, kg, lr);

    // ---- epilogue1: bias+ReLU, LN1 stats, write LN rows back to in_s ----
    const int cbase = w * 64 + lr * 4;                  // 4 contiguous cols
    const f32x4 c1v = *(const f32x4*)(P.cb1 + cbase);
    const f32x4 g1v = *(const f32x4*)(P.g1 + cbase);
    const f32x4 b1v = *(const f32x4*)(P.b1 + cbase);

    #pragma unroll
    for (int m = 0; m < 4; m++) {
        #pragma unroll
        for (int reg = 0; reg < 4; reg++) {
            float s = 0.f, q = 0.f;
            #pragma unroll
            for (int n = 0; n < 4; n++) {
                const float v = fmaxf(acc[m][n][reg] + c1v[n], 0.f);
                acc[m][n][reg] = v;
                s += v; q += v * v;
            }
            #pragma unroll
            for (int msk = 1; msk < 16; msk <<= 1) { s += __shfl_xor(s, msk); q += __shfl_xor(q, msk); }
            if (lr == 0) {
                const int r = m * 16 + kg * 4 + reg;
                red_s[w][r] = s; red_q[w][r] = q;
            }
        }
    }
    __syncthreads();                                       // x-tile in in_s now dead
    if (tid < 64) {
        const float s = red_s[0][tid] + red_s[1][tid] + red_s[2][tid] + red_s[3][tid];
        const float q = red_q[0][tid] + red_q[1][tid] + red_q[2][tid] + red_q[3][tid];
        const float mm = s * (1.f / 256.f);
        const float var = fmaxf(q * (1.f / 256.f) - mm * mm, 0.f);
        row_m[tid] = mm;
        row_rs[tid] = rsqrtf(var + LN_EPS);
    }
    if (tid >= 128 && tid < 192) {                         // zero c1 rows 64,65
        short8 z = {};
        *(short8*)(in_s + 64 * 256 + (tid - 128) * 8) = z;
    }
    __syncthreads();

    // write LN1 rows (bf16, short4 per (m,reg)) into in_s rows 0..63
    #pragma unroll
    for (int m = 0; m < 4; m++) {
        #pragma unroll
        for (int reg = 0; reg < 4; reg++) {
            const int r1 = m * 16 + kg * 4 + reg;
            const int tg = t0 - 1 + r1;
            const bool ok = (tg >= 0) && (tg < Tlen);
            const float mm = row_m[r1], rs = row_rs[r1];
            short4v o;
            #pragma unroll
            for (int n = 0; n < 4; n++) {
                const float v = ok ? (acc[m][n][reg] - mm) * rs * g1v[n] + b1v[n] : 0.f;
                o[n] = f2bf(v);
            }
            *(short4v*)(in_s + r1 * 256 + (((cbase >> 3) ^ (r1 & 7)) << 3) + (cbase & 7)) = o;
        }
    }
    __syncthreads();

    // ---- conv2 K-loop ----
    #pragma unroll
    for (int m = 0; m < 4; m++)
        #pragma unroll
        for (int n = 0; n < 4; n++)
            acc[m][n] = (f32x4){0.f, 0.f, 0.f, 0.f};
    conv_kloop(in_s, (const short8*)P.wb2, acc, w, lane, kg, lr);

    // ---- epilogue2: bias+ReLU, LN2, dot(lw)+lb+ReLU -> scalar ----
    const f32x4 c2v = *(const f32x4*)(P.cb2 + cbase);
    const f32x4 g2v = *(const f32x4*)(P.g2 + cbase);
    const f32x4 b2v = *(const f32x4*)(P.b2 + cbase);
    const f32x4 lwv = *(const f32x4*)(P.lw + cbase);

    #pragma unroll
    for (int m = 0; m < 4; m++) {
        #pragma unroll
        for (int reg = 0; reg < 4; reg++) {
            float s = 0.f, q = 0.f;
            #pragma unroll
            for (int n = 0; n < 4; n++) {
                const float v = fmaxf(acc[m][n][reg] + c2v[n], 0.f);
                acc[m][n][reg] = v;
                s += v; q += v * v;
            }
            #pragma unroll
            for (int msk = 1; msk < 16; msk <<= 1) { s += __shfl_xor(s, msk); q += __shfl_xor(q, msk); }
            if (lr == 0) {
                const int r = m * 16 + kg * 4 + reg;
                red_s[w][r] = s; red_q[w][r] = q;
            }
        }
    }
    __syncthreads();
    if (tid < 64) {
        const float s = red_s[0][tid] + red_s[1][tid] + red_s[2][tid] + red_s[3][tid];
        const float q = red_q[0][tid] + red_q[1][tid] + red_q[2][tid] + red_q[3][tid];
        const float mm = s * (1.f / 256.f);
        const float var = fmaxf(q * (1.f / 256.f) - mm * mm, 0.f);
        row_m[tid] = mm;
        row_rs[tid] = rsqrtf(var + LN_EPS);
    }
    __syncthreads();
    #pragma unroll
    for (int m = 0; m < 4; m++) {
        #pragma unroll
        for (int reg = 0; reg < 4; reg++) {
            const int r = m * 16 + kg * 4 + reg;
            const float mm = row_m[r], rs = row_rs[r];
            float p = 0.f;
            #pragma unroll
            for (int n = 0; n < 4; n++)
                p += ((acc[m][n][reg] - mm) * rs * g2v[n] + b2v[n]) * lwv[n];
            #pragma unroll
            for (int msk = 1; msk < 16; msk <<= 1) p += __shfl_xor(p, msk);
            if (lr == 0) dot_p[w][r] = p;
        }
    }
    __syncthreads();
    if (tid < 62) {
        const int t = t0 + tid;
        if (t < Tlen) {
            const float p = dot_p[0][tid] + dot_p[1][tid] + dot_p[2][tid] + dot_p[3][tid] + P.lb[0];
            P.out[(size_t)b * Tlen + t] = fmaxf(p, 0.f);
        }
    }
}

extern "C" void kernel_launch(void* const* d_in, const int* in_sizes, int n_in,
                              void* d_out, int out_size, void* d_ws, size_t ws_size,
                              hipStream_t stream) {
    const float* x        = (const float*)d_in[0];
    const int*   d_target = (const int*)d_in[1];
    const float* e_target = (const float*)d_in[2];
    const float* p_target = (const float*)d_in[3];

    const float* const* P = (const float* const*)d_in;
    const float* en_emb  = (const float*)d_in[35];
    const float* pi_emb  = (const float*)d_in[36];
    const float* en_bins = (const float*)d_in[37];
    const float* pi_bins = (const float*)d_in[38];

    float* out = (float*)d_out;
    float* h        = out;                                   // B*T*D fp32
    float* log_dur  = out + (size_t)B * T * D;               // B*L
    float* pitch    = log_dur + (size_t)B * L;               // B*T
    float* energy   = pitch + (size_t)B * T;                 // B*T

    short* wbs  = (short*)d_ws;                              // 6 * WFRAGS * 8 shorts
    int*   cum  = (int*)(wbs + (size_t)6 * WFRAGS * 8);      // B*L
    int*   gidx = cum + B * L;                               // B*T
    int*   eidx = gidx + B * T;                              // B*T
    int*   pidx = eidx + B * T;                              // B*T
    float* zvp  = (float*)(pidx + B * T);                    // 1

    // ONE preamble dispatch: wprep + cumsum/idx + zv
    preamble_kernel<<<PRE_TOTAL, BDIM, 0, stream>>>(
        P[5], P[9], P[15], P[19], P[25], P[29],
        d_target, e_target, en_bins, p_target, pi_bins,
        P[16], P[17], P[18], P[19], P[20], P[21], P[22], P[23], P[24],
        wbs, cum, gidx, eidx, pidx, zvp);

    PredParams dur_p = { wbs + (size_t)0 * WFRAGS * 8, wbs + (size_t)1 * WFRAGS * 8,
                         P[6], P[7], P[8], P[10], P[11], P[12], P[13], P[14],
                         nullptr, nullptr, nullptr, log_dur, L, 0 };
    PredParams en_p  = { wbs + (size_t)2 * WFRAGS * 8, wbs + (size_t)3 * WFRAGS * 8,
                         P[16], P[17], P[18], P[20], P[21], P[22], P[23], P[24],
                         nullptr, nullptr, zvp, energy, T, 1 };
    PredParams pi_p  = { wbs + (size_t)4 * WFRAGS * 8, wbs + (size_t)5 * WFRAGS * 8,
                         P[26], P[27], P[28], P[30], P[31], P[32], P[33], P[34],
                         eidx, en_emb, nullptr, pitch, T, 1 };

    // ONE mega dispatch: predictors first, final_h streaming tail
    mega_kernel<<<N_PRED + N_FH, BDIM, 0, stream>>>(
        x, gidx, cum, eidx, pidx, en_emb, pi_emb, h, dur_p, en_p, pi_p);
}